// Round 11
// baseline (92.716 us; speedup 1.0000x reference)
//
#include <hip/hip_runtime.h>

// Chamfer distance via MFMA, two-pass row-min, B=8, N=M=8192.
// D[i,j] = sq_i + sq_j - 2<pi,pj> as one K=16 bf16 dot (hi/lo split, fp32-class):
//   A row-form: [xh,xh,xl, yh,yh,yl, zh,zh,zl, 1,1, sh,sl, 0,0,0]  (built in-kernel)
//   B col-form: [Xh,Xl,Xh, Yh,Yl,Yh, Zh,Zl,Zh, Sh,Sl, 1,1, 0,0,0]  (-2 on coords)
// R11 delta vs R9: RPW 64->128 (4 A-frags/wave) halves the shared B-load
// stream (R9/R10 A/B showed load traffic is the lever); SPLITJ 4->8 keeps
// 8192 waves; launch_bounds(256,3) gives the ~154-reg live set headroom;
// copy-free qa/qb prefetch rotation kills the per-iter v_movs.

typedef unsigned int uint;
typedef unsigned short ushort;
typedef __attribute__((ext_vector_type(8))) short short8;
typedef __attribute__((ext_vector_type(16))) float f32x16;

#define B_     8
#define N_     8192
#define M_     8192
#define BN     (B_ * N_)        // 65536
#define SPLITJ 8
#define JCH    (M_ / SPLITJ)    // 1024 cols per wave sweep
#define JT     (JCH / 32)       // 32 col-tiles
#define RPW    128              // rows per wave (4 A-frags)
#define WAVES  4
#define RPB    (RPW * WAVES)    // 512 rows per block
#define RBLK   (N_ / RPB)       // 16 row-blocks per batch

__device__ __forceinline__ ushort f2bf(float f) {   // RNE f32->bf16
    uint u = __float_as_uint(f);
    return (ushort)((u + 0x7FFFu + ((u >> 16) & 1u)) >> 16);
}
__device__ __forceinline__ float bf2f(ushort h) {
    return __uint_as_float(((uint)h) << 16);
}

// Col-form pack for both clouds in one launch (coords scaled by -2, sq unscaled).
// grid = (BN/256, 2)
__global__ void prep_kernel(const float* __restrict__ x1, const float* __restrict__ x2,
                            ushort* __restrict__ v1, ushort* __restrict__ v2) {
    int i = blockIdx.x * 256 + threadIdx.x;
    const float* __restrict__ xyz = blockIdx.y ? x2 : x1;
    ushort* __restrict__ vec = blockIdx.y ? v2 : v1;
    float x = xyz[3 * i], y = xyz[3 * i + 1], z = xyz[3 * i + 2];
    float s = fmaf(x, x, fmaf(y, y, z * z));
    x *= -2.0f; y *= -2.0f; z *= -2.0f;
    ushort xh = f2bf(x), xl = f2bf(x - bf2f(xh));
    ushort yh = f2bf(y), yl = f2bf(y - bf2f(yh));
    ushort zh = f2bf(z), zl = f2bf(z - bf2f(zh));
    ushort sh = f2bf(s), sl = f2bf(s - bf2f(sh));
    const uint one = 0x3F80u;
    uint4* dst = (uint4*)(vec + (size_t)i * 16);
    dst[0] = make_uint4((uint)xh | ((uint)xl << 16), (uint)xh | ((uint)yh << 16),
                        (uint)yl | ((uint)yh << 16), (uint)zh | ((uint)zl << 16));
    dst[1] = make_uint4((uint)zh | ((uint)sh << 16), (uint)sl | (one << 16),
                        one, 0u);
}

// Build A row-frag for global row g, k-half h, from raw xyz.
__device__ __forceinline__ short8 build_a(const float* __restrict__ own, int g, int h) {
    float x = own[3 * g], y = own[3 * g + 1], z = own[3 * g + 2];
    float s = fmaf(x, x, fmaf(y, y, z * z));
    ushort xh = f2bf(x), xl = f2bf(x - bf2f(xh));
    ushort yh = f2bf(y), yl = f2bf(y - bf2f(yh));
    ushort zh = f2bf(z), zl = f2bf(z - bf2f(zh));
    ushort sh = f2bf(s), sl = f2bf(s - bf2f(sh));
    const ushort one = 0x3F80;
    short8 a;
    a[0] = (short)(h ? zl  : xh);
    a[1] = (short)(h ? one : xh);
    a[2] = (short)(h ? one : xl);
    a[3] = (short)(h ? sh  : yh);
    a[4] = (short)(h ? sl  : yh);
    a[5] = (short)(h ? 0   : yl);
    a[6] = (short)(h ? 0   : zh);
    a[7] = (short)(h ? 0   : zh);
    return a;
}

// One tile-pair step for all 4 A-frags.
__device__ __forceinline__ void step4(const short8& a0, const short8& a1,
                                      const short8& a2, const short8& a3,
                                      const short8& q0, const short8& q1,
                                      const f32x16& zc,
                                      f32x16& rm0, f32x16& rm1,
                                      f32x16& rm2, f32x16& rm3) {
    f32x16 d0 = __builtin_amdgcn_mfma_f32_32x32x16_bf16(a0, q0, zc, 0, 0, 0);
    f32x16 d1 = __builtin_amdgcn_mfma_f32_32x32x16_bf16(a0, q1, zc, 0, 0, 0);
#pragma unroll
    for (int k = 0; k < 16; ++k)
        rm0[k] = fminf(fminf(d0[k], d1[k]), rm0[k]);   // min3-fusable
    f32x16 d2 = __builtin_amdgcn_mfma_f32_32x32x16_bf16(a1, q0, zc, 0, 0, 0);
    f32x16 d3 = __builtin_amdgcn_mfma_f32_32x32x16_bf16(a1, q1, zc, 0, 0, 0);
#pragma unroll
    for (int k = 0; k < 16; ++k)
        rm1[k] = fminf(fminf(d2[k], d3[k]), rm1[k]);
    f32x16 d4 = __builtin_amdgcn_mfma_f32_32x32x16_bf16(a2, q0, zc, 0, 0, 0);
    f32x16 d5 = __builtin_amdgcn_mfma_f32_32x32x16_bf16(a2, q1, zc, 0, 0, 0);
#pragma unroll
    for (int k = 0; k < 16; ++k)
        rm2[k] = fminf(fminf(d4[k], d5[k]), rm2[k]);
    f32x16 d6 = __builtin_amdgcn_mfma_f32_32x32x16_bf16(a3, q0, zc, 0, 0, 0);
    f32x16 d7 = __builtin_amdgcn_mfma_f32_32x32x16_bf16(a3, q1, zc, 0, 0, 0);
#pragma unroll
    for (int k = 0; k < 16; ++k)
        rm3[k] = fminf(fminf(d6[k], d7[k]), rm3[k]);
}

// grid = (B_*RBLK, SPLITJ, 2) = (128, 8, 2). 4 waves/block, 128 rows/wave.
__global__ __launch_bounds__(256, 3)
void cham_mfma7(const float* __restrict__ xyz1, const float* __restrict__ xyz2,
                const short8* __restrict__ Bv1,  // col-form pack of cloud1
                const short8* __restrict__ Bv2,  // col-form pack of cloud2
                float* __restrict__ part) {      // [2][SPLITJ][BN]
    const int tid  = threadIdx.x;
    const int wave = tid >> 6;
    const int lane = tid & 63;
    const int half = lane >> 5;
    const int lc   = lane & 31;

    const int b   = blockIdx.x / RBLK;
    const int rb  = blockIdx.x % RBLK;
    const int dir = blockIdx.z;

    const float*  own = dir ? xyz2 : xyz1;   // rows from this cloud
    const short8* Bv  = dir ? Bv1  : Bv2;    // sweep the other cloud

    const int row0 = rb * RPB + wave * RPW;
    const int gr   = b * N_ + row0;

    const short8 a0 = build_a(own, gr + lc,      half);
    const short8 a1 = build_a(own, gr + 32 + lc, half);
    const short8 a2 = build_a(own, gr + 64 + lc, half);
    const short8 a3 = build_a(own, gr + 96 + lc, half);

    f32x16 zc;
#pragma unroll
    for (int k = 0; k < 16; ++k) zc[k] = 0.0f;
    f32x16 rm0, rm1, rm2, rm3;
#pragma unroll
    for (int k = 0; k < 16; ++k) {
        rm0[k] = 3.0e38f; rm1[k] = 3.0e38f; rm2[k] = 3.0e38f; rm3[k] = 3.0e38f;
    }

    const short8* bp = Bv + ((size_t)b * M_ + (size_t)blockIdx.y * JCH + lc) * 2 + half;

    // Copy-free 2-pair-ahead prefetch rotation. JT = 32, divisible by 4.
    short8 qa0 = bp[0 * 64],  qa1 = bp[1 * 64];
    short8 qb0 = bp[2 * 64],  qb1 = bp[3 * 64];

    for (int t = 0; t < JT - 4; t += 4) {
        step4(a0, a1, a2, a3, qa0, qa1, zc, rm0, rm1, rm2, rm3);
        qa0 = bp[(t + 4) * 64];
        qa1 = bp[(t + 5) * 64];
        step4(a0, a1, a2, a3, qb0, qb1, zc, rm0, rm1, rm2, rm3);
        qb0 = bp[(t + 6) * 64];
        qb1 = bp[(t + 7) * 64];
    }
    step4(a0, a1, a2, a3, qa0, qa1, zc, rm0, rm1, rm2, rm3);
    step4(a0, a1, a2, a3, qb0, qb1, zc, rm0, rm1, rm2, rm3);

    // Butterfly min across the 32 col-lanes of each half-group.
#pragma unroll
    for (int k = 0; k < 16; ++k) {
#pragma unroll
        for (int s2 = 16; s2 >= 1; s2 >>= 1) {
            rm0[k] = fminf(rm0[k], __shfl_xor(rm0[k], s2));
            rm1[k] = fminf(rm1[k], __shfl_xor(rm1[k], s2));
            rm2[k] = fminf(rm2[k], __shfl_xor(rm2[k], s2));
            rm3[k] = fminf(rm3[k], __shfl_xor(rm3[k], s2));
        }
    }

    // C layout: row = (k&3) + 8*(k>>2) + 4*half, col = lane&31.
    float* p = part + ((size_t)dir * SPLITJ + blockIdx.y) * BN + gr;
    if (lc == 0) {
#pragma unroll
        for (int k = 0; k < 16; ++k) {
            int rr = (k & 3) + 8 * (k >> 2) + 4 * half;
            p[rr]      = rm0[k];
            p[32 + rr] = rm1[k];
            p[64 + rr] = rm2[k];
            p[96 + rr] = rm3[k];
        }
    }
}

// 8-way min over j-splits. i in [0, 2*BN).
__global__ void decode_kernel(const float* __restrict__ part, float* __restrict__ out) {
    int i = blockIdx.x * 256 + threadIdx.x;
    int dir = i / BN;
    int ii  = i - dir * BN;
    const float* p = part + (size_t)dir * SPLITJ * BN + ii;
    float m0 = fminf(p[0],             p[(size_t)BN]);
    float m1 = fminf(p[(size_t)2 * BN], p[(size_t)3 * BN]);
    float m2 = fminf(p[(size_t)4 * BN], p[(size_t)5 * BN]);
    float m3 = fminf(p[(size_t)6 * BN], p[(size_t)7 * BN]);
    out[i] = fminf(fminf(m0, m1), fminf(m2, m3));
}

extern "C" void kernel_launch(void* const* d_in, const int* in_sizes, int n_in,
                              void* d_out, int out_size, void* d_ws, size_t ws_size,
                              hipStream_t stream) {
    const float* xyz1 = (const float*)d_in[0];
    const float* xyz2 = (const float*)d_in[1];
    float* out = (float*)d_out;

    // ws: Bv1 (2MB) | Bv2 (2MB) | part (2*8*BN*4 = 4MB)
    ushort* Bv1 = (ushort*)d_ws;
    ushort* Bv2 = Bv1 + (size_t)BN * 16;
    float*  part = (float*)(Bv2 + (size_t)BN * 16);

    dim3 pgrid(BN / 256, 2);
    prep_kernel<<<pgrid, 256, 0, stream>>>(xyz1, xyz2, Bv1, Bv2);

    dim3 grid(B_ * RBLK, SPLITJ, 2);   // (128, 8, 2)
    cham_mfma7<<<grid, 256, 0, stream>>>(xyz1, xyz2,
                                         (const short8*)Bv1, (const short8*)Bv2, part);

    decode_kernel<<<(2 * BN) / 256, 256, 0, stream>>>(part, out);
}

// Round 12
// 54.238 us; speedup vs baseline: 1.7094x; 1.7094x over previous
//
#include <hip/hip_runtime.h>

// Chamfer distance via MFMA, two-pass row-min, B=8, N=M=8192.
// D[i,j] = sq_i + sq_j - 2<pi,pj> as one K=16 bf16 dot (hi/lo split, fp32-class):
//   A row-form: [xh,xh,xl, yh,yh,yl, zh,zh,zl, 1,1, sh,sl, 0,0,0]  (built in-kernel)
//   B col-form: [Xh,Xl,Xh, Yh,Yl,Yh, Zh,Zl,Zh, Sh,Sl, 1,1, 0,0,0]  (-2 on coords)
// R12 delta vs R9: software-pipelined consume — tile t's 32 mins run AFTER
// tile t+1's MFMAs are issued (alternating named d/e sets, copy-free q0/q1
// rotation). Breaks the MFMA->min critical path that stalled ~45% of the
// wave period. launch_bounds(256,3): live set ~140 regs, cap ~170 (no spill).

typedef unsigned int uint;
typedef unsigned short ushort;
typedef __attribute__((ext_vector_type(8))) short short8;
typedef __attribute__((ext_vector_type(16))) float f32x16;

#define B_     8
#define N_     8192
#define M_     8192
#define BN     (B_ * N_)        // 65536
#define SPLITJ 4
#define JCH    (M_ / SPLITJ)    // 2048 cols per wave sweep
#define JT     (JCH / 32)       // 64 col-tiles
#define RPW    64               // rows per wave (2 A-frags)
#define WAVES  4
#define RPB    (RPW * WAVES)    // 256 rows per block
#define RBLK   (N_ / RPB)       // 32 row-blocks per batch

__device__ __forceinline__ ushort f2bf(float f) {   // RNE f32->bf16
    uint u = __float_as_uint(f);
    return (ushort)((u + 0x7FFFu + ((u >> 16) & 1u)) >> 16);
}
__device__ __forceinline__ float bf2f(ushort h) {
    return __uint_as_float(((uint)h) << 16);
}

// Col-form pack for both clouds in one launch (coords scaled by -2, sq unscaled).
// grid = (BN/256, 2)
__global__ void prep_kernel(const float* __restrict__ x1, const float* __restrict__ x2,
                            ushort* __restrict__ v1, ushort* __restrict__ v2) {
    int i = blockIdx.x * 256 + threadIdx.x;
    const float* __restrict__ xyz = blockIdx.y ? x2 : x1;
    ushort* __restrict__ vec = blockIdx.y ? v2 : v1;
    float x = xyz[3 * i], y = xyz[3 * i + 1], z = xyz[3 * i + 2];
    float s = fmaf(x, x, fmaf(y, y, z * z));
    x *= -2.0f; y *= -2.0f; z *= -2.0f;
    ushort xh = f2bf(x), xl = f2bf(x - bf2f(xh));
    ushort yh = f2bf(y), yl = f2bf(y - bf2f(yh));
    ushort zh = f2bf(z), zl = f2bf(z - bf2f(zh));
    ushort sh = f2bf(s), sl = f2bf(s - bf2f(sh));
    const uint one = 0x3F80u;
    uint4* dst = (uint4*)(vec + (size_t)i * 16);
    dst[0] = make_uint4((uint)xh | ((uint)xl << 16), (uint)xh | ((uint)yh << 16),
                        (uint)yl | ((uint)yh << 16), (uint)zh | ((uint)zl << 16));
    dst[1] = make_uint4((uint)zh | ((uint)sh << 16), (uint)sl | (one << 16),
                        one, 0u);
}

// Build A row-frag for global row g, k-half h, from raw xyz.
__device__ __forceinline__ short8 build_a(const float* __restrict__ own, int g, int h) {
    float x = own[3 * g], y = own[3 * g + 1], z = own[3 * g + 2];
    float s = fmaf(x, x, fmaf(y, y, z * z));
    ushort xh = f2bf(x), xl = f2bf(x - bf2f(xh));
    ushort yh = f2bf(y), yl = f2bf(y - bf2f(yh));
    ushort zh = f2bf(z), zl = f2bf(z - bf2f(zh));
    ushort sh = f2bf(s), sl = f2bf(s - bf2f(sh));
    const ushort one = 0x3F80;
    short8 a;
    a[0] = (short)(h ? zl  : xh);
    a[1] = (short)(h ? one : xh);
    a[2] = (short)(h ? one : xl);
    a[3] = (short)(h ? sh  : yh);
    a[4] = (short)(h ? sl  : yh);
    a[5] = (short)(h ? 0   : yl);
    a[6] = (short)(h ? 0   : zh);
    a[7] = (short)(h ? 0   : zh);
    return a;
}

// grid = (B_*RBLK, SPLITJ, 2) = (256, 4, 2). 4 waves/block, 64 rows/wave.
__global__ __launch_bounds__(256, 3)
void cham_mfma8(const float* __restrict__ xyz1, const float* __restrict__ xyz2,
                const short8* __restrict__ Bv1,  // col-form pack of cloud1
                const short8* __restrict__ Bv2,  // col-form pack of cloud2
                float* __restrict__ part) {      // [2][SPLITJ][BN]
    const int tid  = threadIdx.x;
    const int wave = tid >> 6;
    const int lane = tid & 63;
    const int half = lane >> 5;
    const int lc   = lane & 31;

    const int b   = blockIdx.x / RBLK;
    const int rb  = blockIdx.x % RBLK;
    const int dir = blockIdx.z;

    const float*  own = dir ? xyz2 : xyz1;   // rows from this cloud
    const short8* Bv  = dir ? Bv1  : Bv2;    // sweep the other cloud

    const int row0 = rb * RPB + wave * RPW;
    const int gr   = b * N_ + row0;

    const short8 a0 = build_a(own, gr + lc, half);
    const short8 a1 = build_a(own, gr + 32 + lc, half);

    f32x16 zc;
#pragma unroll
    for (int k = 0; k < 16; ++k) zc[k] = 0.0f;
    f32x16 rm0, rm1;
#pragma unroll
    for (int k = 0; k < 16; ++k) { rm0[k] = 3.0e38f; rm1[k] = 3.0e38f; }

    const short8* bp = Bv + ((size_t)b * M_ + (size_t)blockIdx.y * JCH + lc) * 2 + half;

    // --- software pipeline: consume tile t AFTER issuing tile t+1's MFMAs ---
    short8 q0 = bp[0];
    short8 q1 = bp[64];
    f32x16 d0 = __builtin_amdgcn_mfma_f32_32x32x16_bf16(a0, q0, zc, 0, 0, 0);
    f32x16 d1 = __builtin_amdgcn_mfma_f32_32x32x16_bf16(a1, q0, zc, 0, 0, 0);

    for (int t = 0; t < JT - 2; t += 2) {
        // half-step A: issue tile t+1 (from q1), consume tile t (d), load t+2
        f32x16 e0 = __builtin_amdgcn_mfma_f32_32x32x16_bf16(a0, q1, zc, 0, 0, 0);
        f32x16 e1 = __builtin_amdgcn_mfma_f32_32x32x16_bf16(a1, q1, zc, 0, 0, 0);
        q0 = bp[(t + 2) * 64];
#pragma unroll
        for (int k = 0; k < 16; ++k) {
            rm0[k] = fminf(rm0[k], d0[k]);
            rm1[k] = fminf(rm1[k], d1[k]);
        }
        // half-step B: issue tile t+2 (from q0), consume tile t+1 (e), load t+3
        d0 = __builtin_amdgcn_mfma_f32_32x32x16_bf16(a0, q0, zc, 0, 0, 0);
        d1 = __builtin_amdgcn_mfma_f32_32x32x16_bf16(a1, q0, zc, 0, 0, 0);
        q1 = bp[(t + 3) * 64];
#pragma unroll
        for (int k = 0; k < 16; ++k) {
            rm0[k] = fminf(rm0[k], e0[k]);
            rm1[k] = fminf(rm1[k], e1[k]);
        }
    }
    {   // epilogue: tile JT-1 from q1, then consume tiles JT-2 (d) and JT-1 (e)
        f32x16 e0 = __builtin_amdgcn_mfma_f32_32x32x16_bf16(a0, q1, zc, 0, 0, 0);
        f32x16 e1 = __builtin_amdgcn_mfma_f32_32x32x16_bf16(a1, q1, zc, 0, 0, 0);
#pragma unroll
        for (int k = 0; k < 16; ++k) {
            rm0[k] = fminf(rm0[k], d0[k]);
            rm1[k] = fminf(rm1[k], d1[k]);
        }
#pragma unroll
        for (int k = 0; k < 16; ++k) {
            rm0[k] = fminf(rm0[k], e0[k]);
            rm1[k] = fminf(rm1[k], e1[k]);
        }
    }

    // Butterfly min across the 32 col-lanes of each half-group.
#pragma unroll
    for (int k = 0; k < 16; ++k) {
#pragma unroll
        for (int s2 = 16; s2 >= 1; s2 >>= 1) {
            rm0[k] = fminf(rm0[k], __shfl_xor(rm0[k], s2));
            rm1[k] = fminf(rm1[k], __shfl_xor(rm1[k], s2));
        }
    }

    // C layout: row = (k&3) + 8*(k>>2) + 4*half, col = lane&31.
    float* p = part + ((size_t)dir * SPLITJ + blockIdx.y) * BN + gr;
    if (lc == 0) {
#pragma unroll
        for (int k = 0; k < 16; ++k) {
            int rr = (k & 3) + 8 * (k >> 2) + 4 * half;
            p[rr]      = rm0[k];
            p[32 + rr] = rm1[k];
        }
    }
}

// 4-way min over j-splits. i in [0, 2*BN).
__global__ void decode_kernel(const float* __restrict__ part, float* __restrict__ out) {
    int i = blockIdx.x * 256 + threadIdx.x;
    int dir = i / BN;
    int ii  = i - dir * BN;
    const float* p = part + (size_t)dir * SPLITJ * BN + ii;
    out[i] = fminf(fminf(p[0], p[(size_t)BN]),
                   fminf(p[(size_t)2 * BN], p[(size_t)3 * BN]));
}

extern "C" void kernel_launch(void* const* d_in, const int* in_sizes, int n_in,
                              void* d_out, int out_size, void* d_ws, size_t ws_size,
                              hipStream_t stream) {
    const float* xyz1 = (const float*)d_in[0];
    const float* xyz2 = (const float*)d_in[1];
    float* out = (float*)d_out;

    // ws: Bv1 (2MB) | Bv2 (2MB) | part (2MB)
    ushort* Bv1 = (ushort*)d_ws;
    ushort* Bv2 = Bv1 + (size_t)BN * 16;
    float*  part = (float*)(Bv2 + (size_t)BN * 16);

    dim3 pgrid(BN / 256, 2);
    prep_kernel<<<pgrid, 256, 0, stream>>>(xyz1, xyz2, Bv1, Bv2);

    dim3 grid(B_ * RBLK, SPLITJ, 2);   // (256, 4, 2)
    cham_mfma8<<<grid, 256, 0, stream>>>(xyz1, xyz2,
                                         (const short8*)Bv1, (const short8*)Bv2, part);

    decode_kernel<<<(2 * BN) / 256, 256, 0, stream>>>(part, out);
}